// Round 3
// baseline (164.684 us; speedup 1.0000x reference)
//
#include <hip/hip_runtime.h>

// Problem constants (from reference setup_inputs): B=16, C=4, H=W=1024.
#define B_  16
#define H_  1024
#define W_  1024
#define OW_ (2 * W_)       // 2048
#define OH_ (2 * H_)       // 2048

// Block layout: 34816 blocks total = 17 * 2048.
//   g % 17 == 16 -> cons block   (2048 blocks):  compute cons plane once,
//                                 broadcast-store to all 16 batches.
//   g % 17 != 16 -> shuffle block (32768 blocks): pixel-shuffle only.
// Interleaving cons blocks through the dispatch spreads their write
// traffic across the kernel instead of creating a serialized tail.

__global__ __launch_bounds__(256) void unsqueeze_cons_kernel(
    const float* __restrict__ in,
    float* __restrict__ out_x,
    float* __restrict__ out_cons)
{
    const int g = blockIdx.x;
    const int q = g / 17;
    const int rm = g - q * 17;
    const long chanStride = (long)H_ * W_;           // 1,048,576

    if (rm != 16) {
        // ---------------- shuffle block ----------------
        const int sb = q * 16 + rm;                  // 0..32767
        const long idx = (long)sb * 256 + threadIdx.x;
        const int c2 = (int)(idx & (W_ / 2 - 1));    // 0..511
        const int r  = (int)((idx >> 9) & (H_ - 1)); // 0..1023
        const int b  = (int)(idx >> 19);             // 0..15

        const long base = ((long)b * 4) * chanStride + (long)r * W_ + (long)c2 * 2;
        const float2 ch0 = *reinterpret_cast<const float2*>(in + base);
        const float2 ch1 = *reinterpret_cast<const float2*>(in + base + chanStride);
        const float2 ch2 = *reinterpret_cast<const float2*>(in + base + 2 * chanStride);
        const float2 ch3 = *reinterpret_cast<const float2*>(in + base + 3 * chanStride);

        // out_x[b, 2r+dr, 2c+dc] = in[b, dr+2*dc, r, c]
        const long orow0 = (long)b * OH_ * OW_ + (long)(2 * r) * OW_ + (long)c2 * 4;
        const long orow1 = orow0 + OW_;
        float4 x0 = {ch0.x, ch2.x, ch0.y, ch2.y};
        float4 x1 = {ch1.x, ch3.x, ch1.y, ch3.y};
        *reinterpret_cast<float4*>(out_x + orow0) = x0;
        *reinterpret_cast<float4*>(out_x + orow1) = x1;
    } else {
        // ---------------- cons block ----------------
        const long idx = (long)q * 256 + threadIdx.x;   // 0..524287
        const int c2 = (int)(idx & (W_ / 2 - 1));       // 0..511
        const int r  = (int)(idx >> 9);                 // 0..1023

        const long base0 = (long)r * W_ + (long)c2 * 2;
        const float2 a0 = *reinterpret_cast<const float2*>(in + base0);
        const float2 a1 = *reinterpret_cast<const float2*>(in + base0 + chanStride);
        const float2 a2 = *reinterpret_cast<const float2*>(in + base0 + 2 * chanStride);

        const float k3 = 1.0f / 3.0f;
        float2 s2, s1, s0;
        s2.x = (a0.x + 1.0f) * 0.5f;
        s2.y = (a0.y + 1.0f) * 0.5f;
        s1.x = (a0.x + a1.x + 1.0f) * k3;
        s1.y = (a0.y + a1.y + 1.0f) * k3;
        s0.x = (a0.x + a1.x + a2.x + 1.0f) * 0.25f;
        s0.y = (a0.y + a1.y + a2.y + 1.0f) * 0.25f;

        // cons row 2r   : (2c)->1.0, (2c+1)->s1
        // cons row 2r+1 : (2c)->s2,  (2c+1)->s0
        float4 c0 = {1.0f, s1.x, 1.0f, s1.y};
        float4 c1 = {s2.x, s0.x, s2.y, s0.y};

        const long prow0 = (long)(2 * r) * OW_ + (long)c2 * 4;
        const long prow1 = prow0 + OW_;
        #pragma unroll
        for (int b2 = 0; b2 < B_; ++b2) {
            const long boff = (long)b2 * OH_ * OW_;
            *reinterpret_cast<float4*>(out_cons + boff + prow0) = c0;
            *reinterpret_cast<float4*>(out_cons + boff + prow1) = c1;
        }
    }
}

extern "C" void kernel_launch(void* const* d_in, const int* in_sizes, int n_in,
                              void* d_out, int out_size, void* d_ws, size_t ws_size,
                              hipStream_t stream) {
    const float* in = (const float*)d_in[0];
    float* out_x    = (float*)d_out;                                   // (16,1,2048,2048)
    float* out_cons = (float*)d_out + (long)B_ * OH_ * OW_;            // (16,1,2048,2048)

    const int grid = 17 * 2048;                                        // 34,816 blocks
    unsqueeze_cons_kernel<<<grid, 256, 0, stream>>>(in, out_x, out_cons);
}